// Round 7
// baseline (255.884 us; speedup 1.0000x reference)
//
#include <hip/hip_runtime.h>
#include <hip/hip_bf16.h>

#define UNITS 512
#define SEQ   4096
#define BATCH 32

typedef __attribute__((ext_vector_type(8))) __bf16 bf16x8;
typedef __attribute__((ext_vector_type(4))) float  f32x4;

// 128B-row LDS swizzle: for x in [0,128): swz128(r*128+x) = r*128 + (x ^ ((r&7)<<4)).
// Same forward map on write and read; 16-row fragment reads become exact 2-way (free).
__device__ __forceinline__ int swz128(int l) { return l ^ (((l >> 7) & 7) << 4); }

#define MFMA(A, B, C) __builtin_amdgcn_mfma_f32_16x16x32_bf16(A, B, C, 0, 0, 0)
#define GLL(SRC, DST) __builtin_amdgcn_global_load_lds( \
    (const __attribute__((address_space(1))) void*)(SRC), \
    (__attribute__((address_space(3))) void*)(DST), 16, 0, 0)
#define PK8(X, Y) ({ bf16x8 _o; \
    _o[0]=(__bf16)(X).x; _o[1]=(__bf16)(X).y; _o[2]=(__bf16)(X).z; _o[3]=(__bf16)(X).w; \
    _o[4]=(__bf16)(Y).x; _o[5]=(__bf16)(Y).y; _o[6]=(__bf16)(Y).z; _o[7]=(__bf16)(Y).w; _o; })

// ---------------- K0: Uw [k][n] f32 -> UwTt: 16 tiles (ktile,gx) of 32KB --------
// Tile (t,gx): [n_local 256][k 64] bf16, rows 128B, stored PRE-SWIZZLED (swz128)
// so k_logits stages with linear global_load_lds and reads with swz128.
__global__ void k_bprep(const float* __restrict__ Uw, __bf16* __restrict__ UwTt) {
    const int c  = blockIdx.x;   // 16B chunk within 128B k-row (0..7)
    const int gx = blockIdx.y;   // n half
    const int t  = blockIdx.z;   // k-tile (0..7)
    const int nl = threadIdx.x;  // 0..255
    const int n  = gx * 256 + nl;
    const int k0 = t * 64 + c * 8;
    bf16x8 o;
#pragma unroll
    for (int j = 0; j < 8; j++)
        o[j] = (__bf16)Uw[(size_t)(k0 + j) * UNITS + n];
    char* dst = (char*)UwTt + (size_t)(t * 2 + gx) * 32768 + swz128(nl * 128 + c * 16);
    *(bf16x8*)dst = o;
}

// ---------------- KA: ws_Ws[b][v] = s_prev[b,:] @ Ww[:,v] + Wb[v] + Ub[v] --------
__global__ void k_wsrow(const float* __restrict__ s_prev, const float* __restrict__ Ww,
                        const float* __restrict__ Wb, const float* __restrict__ Ub,
                        float* __restrict__ ws_Ws) {
    __shared__ float sp[UNITS];
    int b = blockIdx.x, t = threadIdx.x;
    sp[t] = s_prev[b * UNITS + t];
    sp[t + 256] = s_prev[b * UNITS + t + 256];
    __syncthreads();
    float a0 = Wb[t] + Ub[t];
    float a1 = Wb[t + 256] + Ub[t + 256];
#pragma unroll 8
    for (int u = 0; u < UNITS; u++) {
        float s = sp[u];
        a0 += s * Ww[u * UNITS + t];
        a1 += s * Ww[u * UNITS + t + 256];
    }
    ws_Ws[b * UNITS + t] = a0;
    ws_Ws[b * UNITS + t + 256] = a1;
}

// ---------------- KB: fused  tanh(Ws + hidden@Uw) @ Vw  ->  logit partials -------
// m201-style 8-phase schedule adapted: 256x256 tile, 8 waves (2Mx4N, wave 128x64),
// BK=64, 8 K-tiles x 4 phases. Per phase: 4 A ds_reads (+8 B at ph0, held in regs)
// | staged issue for next tile | lgkm(0) | setprio+16 MFMA | barrier.
// vmcnt drains once per K-tile, 2-3 phases after issue.
#define NT 8

__launch_bounds__(512, 2)
__global__ void k_logits(const float* __restrict__ hidden, const __bf16* __restrict__ UwTt,
                         const float* __restrict__ wsu, const float* __restrict__ Vw,
                         float* __restrict__ lpart) {
    __shared__ __bf16 Ab[2][256 * 64];   // 32KB per buf, swz128
    __shared__ __bf16 Bb[2][256 * 64];   // 32KB per buf, pre-swizzled source
    __shared__ float  lred[256][4];      // 4KB -> 132KB total, 1 block/CU

    const int tid  = threadIdx.x;
    const int lane = tid & 63, wv = tid >> 6;
    const int wm = wv >> 2, wn = wv & 3;          // 2 x 4 -> wave tile 128x64
    const int l15 = lane & 15, l4 = lane >> 4;

    // block decode: both gx halves of a row-panel land adjacently on one XCD
    const int id = blockIdx.x;                    // 0..1023
    const int gx = (id >> 3) & 1;
    const int y  = ((id >> 4) << 3) | (id & 7);   // 0..511
    const int m0 = y * 256;
    const int b  = m0 >> 12;

    // fragment addressing: xor value depends only on l15&7 (fi*16 = 0 mod 8)
    const int xorv  = (l15 & 7) << 4;
    const int koff0 = (l4 * 16) ^ xorv;
    const int koff1 = (64 + l4 * 16) ^ xorv;
    const int aBase = wm * 16384 + l15 * 128;     // + fi*2048 + koff
    const int bBase = wn * 8192  + l15 * 128;     // + fj*2048 + koff

    // A staging: thread -> row sr (0..255), half sh; 32 f32 per tile
    const int sr = tid >> 1, sh = tid & 1;
    const float* aPtr = hidden + (size_t)(m0 + sr) * UNITS + sh * 32;
    const int wXor = (sr & 7) << 4;
    int wo0 = sr * 128 + (((sh << 6) | 0 ) ^ wXor);
    int wo1 = sr * 128 + (((sh << 6) | 16) ^ wXor);
    int wo2 = sr * 128 + (((sh << 6) | 32) ^ wXor);
    int wo3 = sr * 128 + (((sh << 6) | 48) ^ wXor);

    // B gll: per wave 4KB per tile
    const char* bglBase = (const char*)UwTt + (size_t)gx * 32768 + wv * 4096 + lane * 16;

    f32x4 acc[8][4];
#pragma unroll
    for (int i = 0; i < 8; i++)
#pragma unroll
        for (int j = 0; j < 4; j++) acc[i][j] = (f32x4){0.f, 0.f, 0.f, 0.f};

    // ---- prologue: stage tile 0 into buf 0 ----
    {
        float4 p0 = *(const float4*)(aPtr + 0);
        float4 p1 = *(const float4*)(aPtr + 4);
        float4 p2 = *(const float4*)(aPtr + 8);
        float4 p3 = *(const float4*)(aPtr + 12);
        float4 p4 = *(const float4*)(aPtr + 16);
        float4 p5 = *(const float4*)(aPtr + 20);
        float4 p6 = *(const float4*)(aPtr + 24);
        float4 p7 = *(const float4*)(aPtr + 28);
        GLL(bglBase,        (char*)Bb[0] + wv * 4096);
        GLL(bglBase + 1024, (char*)Bb[0] + wv * 4096 + 1024);
        GLL(bglBase + 2048, (char*)Bb[0] + wv * 4096 + 2048);
        GLL(bglBase + 3072, (char*)Bb[0] + wv * 4096 + 3072);
        *(bf16x8*)((char*)Ab[0] + wo0) = PK8(p0, p1);
        *(bf16x8*)((char*)Ab[0] + wo1) = PK8(p2, p3);
        *(bf16x8*)((char*)Ab[0] + wo2) = PK8(p4, p5);
        *(bf16x8*)((char*)Ab[0] + wo3) = PK8(p6, p7);
        asm volatile("s_waitcnt vmcnt(0) lgkmcnt(0)" ::: "memory");
        __builtin_amdgcn_s_barrier();
    }

#pragma unroll
    for (int kt = 0; kt < NT; ++kt) {
        char* Ac = (char*)Ab[kt & 1];
        char* Bc = (char*)Bb[kt & 1];
        char* An = (char*)Ab[(kt & 1) ^ 1];
        char* Bn = (char*)Bb[(kt & 1) ^ 1];
        const bool st = (kt < NT - 1);
        const float* ap = aPtr + (kt + 1) * 64;
        const char* bs  = bglBase + (size_t)(kt + 1) * 65536;

        bf16x8 bq[4][2];
        bf16x8 af0k0, af0k1, af1k0, af1k1;
        float4 la0, la1, la2, la3, la4, la5, la6, la7;

        // ================= phase 0: fi 0,1 (+ load B-held frags) =================
#pragma unroll
        for (int fj = 0; fj < 4; fj++) {
            bq[fj][0] = *(const bf16x8*)(Bc + bBase + fj * 2048 + koff0);
            bq[fj][1] = *(const bf16x8*)(Bc + bBase + fj * 2048 + koff1);
        }
        af0k0 = *(const bf16x8*)(Ac + aBase + 0 * 2048 + koff0);
        af0k1 = *(const bf16x8*)(Ac + aBase + 0 * 2048 + koff1);
        af1k0 = *(const bf16x8*)(Ac + aBase + 1 * 2048 + koff0);
        af1k1 = *(const bf16x8*)(Ac + aBase + 1 * 2048 + koff1);
        if (st) {
            la0 = *(const float4*)(ap + 0);
            la1 = *(const float4*)(ap + 4);
            la2 = *(const float4*)(ap + 8);
            la3 = *(const float4*)(ap + 12);
            GLL(bs,        Bn + wv * 4096);
            GLL(bs + 1024, Bn + wv * 4096 + 1024);
        }
        asm volatile("s_waitcnt lgkmcnt(0)" ::: "memory");
        __builtin_amdgcn_sched_barrier(0);
        __builtin_amdgcn_s_setprio(1);
#pragma unroll
        for (int fj = 0; fj < 4; fj++) {
            acc[0][fj] = MFMA(af0k0, bq[fj][0], acc[0][fj]);
            acc[0][fj] = MFMA(af0k1, bq[fj][1], acc[0][fj]);
            acc[1][fj] = MFMA(af1k0, bq[fj][0], acc[1][fj]);
            acc[1][fj] = MFMA(af1k1, bq[fj][1], acc[1][fj]);
        }
        __builtin_amdgcn_s_setprio(0);
        __builtin_amdgcn_s_barrier();

        // ================= phase 1: fi 2,3 =================
        af0k0 = *(const bf16x8*)(Ac + aBase + 2 * 2048 + koff0);
        af0k1 = *(const bf16x8*)(Ac + aBase + 2 * 2048 + koff1);
        af1k0 = *(const bf16x8*)(Ac + aBase + 3 * 2048 + koff0);
        af1k1 = *(const bf16x8*)(Ac + aBase + 3 * 2048 + koff1);
        if (st) {
            la4 = *(const float4*)(ap + 16);
            la5 = *(const float4*)(ap + 20);
            la6 = *(const float4*)(ap + 24);
            la7 = *(const float4*)(ap + 28);
            GLL(bs + 2048, Bn + wv * 4096 + 2048);
            GLL(bs + 3072, Bn + wv * 4096 + 3072);
            *(bf16x8*)(An + wo0) = PK8(la0, la1);
            *(bf16x8*)(An + wo1) = PK8(la2, la3);
        }
        asm volatile("s_waitcnt lgkmcnt(0)" ::: "memory");
        __builtin_amdgcn_sched_barrier(0);
        __builtin_amdgcn_s_setprio(1);
#pragma unroll
        for (int fj = 0; fj < 4; fj++) {
            acc[2][fj] = MFMA(af0k0, bq[fj][0], acc[2][fj]);
            acc[2][fj] = MFMA(af0k1, bq[fj][1], acc[2][fj]);
            acc[3][fj] = MFMA(af1k0, bq[fj][0], acc[3][fj]);
            acc[3][fj] = MFMA(af1k1, bq[fj][1], acc[3][fj]);
        }
        __builtin_amdgcn_s_setprio(0);
        __builtin_amdgcn_s_barrier();

        // ================= phase 2: fi 4,5 =================
        af0k0 = *(const bf16x8*)(Ac + aBase + 4 * 2048 + koff0);
        af0k1 = *(const bf16x8*)(Ac + aBase + 4 * 2048 + koff1);
        af1k0 = *(const bf16x8*)(Ac + aBase + 5 * 2048 + koff0);
        af1k1 = *(const bf16x8*)(Ac + aBase + 5 * 2048 + koff1);
        if (st) {
            *(bf16x8*)(An + wo2) = PK8(la4, la5);
        }
        asm volatile("s_waitcnt lgkmcnt(0)" ::: "memory");
        __builtin_amdgcn_sched_barrier(0);
        __builtin_amdgcn_s_setprio(1);
#pragma unroll
        for (int fj = 0; fj < 4; fj++) {
            acc[4][fj] = MFMA(af0k0, bq[fj][0], acc[4][fj]);
            acc[4][fj] = MFMA(af0k1, bq[fj][1], acc[4][fj]);
            acc[5][fj] = MFMA(af1k0, bq[fj][0], acc[5][fj]);
            acc[5][fj] = MFMA(af1k1, bq[fj][1], acc[5][fj]);
        }
        __builtin_amdgcn_s_setprio(0);
        __builtin_amdgcn_s_barrier();

        // ================= phase 3: fi 6,7 (+ tile-boundary drain) ==============
        af0k0 = *(const bf16x8*)(Ac + aBase + 6 * 2048 + koff0);
        af0k1 = *(const bf16x8*)(Ac + aBase + 6 * 2048 + koff1);
        af1k0 = *(const bf16x8*)(Ac + aBase + 7 * 2048 + koff0);
        af1k1 = *(const bf16x8*)(Ac + aBase + 7 * 2048 + koff1);
        if (st) {
            *(bf16x8*)(An + wo3) = PK8(la6, la7);
        }
        asm volatile("s_waitcnt lgkmcnt(0)" ::: "memory");
        __builtin_amdgcn_sched_barrier(0);
        __builtin_amdgcn_s_setprio(1);
#pragma unroll
        for (int fj = 0; fj < 4; fj++) {
            acc[6][fj] = MFMA(af0k0, bq[fj][0], acc[6][fj]);
            acc[6][fj] = MFMA(af0k1, bq[fj][1], acc[6][fj]);
            acc[7][fj] = MFMA(af1k0, bq[fj][0], acc[7][fj]);
            acc[7][fj] = MFMA(af1k1, bq[fj][1], acc[7][fj]);
        }
        __builtin_amdgcn_s_setprio(0);
        if (st) asm volatile("s_waitcnt vmcnt(0)" ::: "memory");  // B glls landed (issued 2-3 phases ago)
        __builtin_amdgcn_s_barrier();
    }

    // epilogue: tanh(acc + Ws+Ub) * Vw, reduce over this block's 256 cols
    float wsub[4], vww[4];
#pragma unroll
    for (int fj = 0; fj < 4; fj++) {
        int n = gx * 256 + wn * 64 + fj * 16 + l15;
        wsub[fj] = wsu[b * UNITS + n];
        vww[fj]  = Vw[n];
    }
#pragma unroll
    for (int fi = 0; fi < 8; fi++) {
#pragma unroll
        for (int r = 0; r < 4; r++) {
            float p = 0.f;
#pragma unroll
            for (int fj = 0; fj < 4; fj++) {
                float x = acc[fi][fj][r] + wsub[fj];
                float e = __expf(2.f * x);
                p += vww[fj] * (1.f - 2.f / (e + 1.f));   // tanh(x)
            }
#pragma unroll
            for (int off = 1; off < 16; off <<= 1) p += __shfl_xor(p, off);
            if (l15 == 0) lred[wm * 128 + fi * 16 + l4 * 4 + r][wn] = p;
        }
    }
    __syncthreads();
    if (tid < 256) {
        float s = lred[tid][0] + lred[tid][1] + lred[tid][2] + lred[tid][3];
        lpart[(size_t)(m0 + tid) * 2 + gx] = s;
    }
}

// ---------------- KC: softmax over seq axis, write weights ----------------------
__global__ void k_softmax(const float* __restrict__ lpart, float* __restrict__ wout) {
    __shared__ float ebuf[SEQ];
    __shared__ float red[8];
    int b = blockIdx.x, t = threadIdx.x;
    int lane = t & 63, wv = t >> 6;
    float m = -1e30f;
#pragma unroll
    for (int i = 0; i < 16; i++) {
        int s = t + i * 256;
        size_t idx = ((size_t)b * SEQ + s) * 2;
        float l = lpart[idx] + lpart[idx + 1];
        ebuf[s] = l;
        m = fmaxf(m, l);
    }
#pragma unroll
    for (int off = 32; off >= 1; off >>= 1) m = fmaxf(m, __shfl_xor(m, off));
    if (lane == 0) red[wv] = m;
    __syncthreads();
    m = fmaxf(fmaxf(red[0], red[1]), fmaxf(red[2], red[3]));
    float zs = 0.f;
#pragma unroll
    for (int i = 0; i < 16; i++) {
        int s = t + i * 256;
        float e = __expf(ebuf[s] - m);
        ebuf[s] = e;
        zs += e;
    }
#pragma unroll
    for (int off = 32; off >= 1; off >>= 1) zs += __shfl_xor(zs, off);
    __syncthreads();
    if (lane == 0) red[wv] = zs;
    __syncthreads();
    float inv = 1.f / (red[0] + red[1] + red[2] + red[3]);
#pragma unroll
    for (int i = 0; i < 16; i++) {
        int s = t + i * 256;
        wout[(size_t)b * SEQ + s] = ebuf[s] * inv;
    }
}

// ---------------- KD: context partials over 128-seq chunks ----------------------
__global__ void k_ctxpart(const float* __restrict__ hidden, const float* __restrict__ wout,
                          float* __restrict__ part) {
    int b = blockIdx.y, c = blockIdx.x, t = threadIdx.x;
    const float* w = wout + (size_t)b * SEQ + c * 128;
    const float* h = hidden + ((size_t)b * SEQ + c * 128) * UNITS;
    float2 acc = make_float2(0.f, 0.f);
#pragma unroll 4
    for (int s = 0; s < 128; s++) {
        float ww = w[s];
        float2 v = ((const float2*)(h + (size_t)s * UNITS))[t];
        acc.x += ww * v.x;
        acc.y += ww * v.y;
    }
    ((float2*)(part + ((size_t)(b * 32 + c)) * UNITS))[t] = acc;
}

// ---------------- KE: reduce partials -> context --------------------------------
__global__ void k_ctxreduce(const float* __restrict__ part, float* __restrict__ ctx) {
    int b = blockIdx.x, t = threadIdx.x;
    float s = 0.f;
#pragma unroll
    for (int c = 0; c < 32; c++) s += part[((size_t)(b * 32 + c)) * UNITS + t];
    ctx[(size_t)b * UNITS + t] = s;
}

extern "C" void kernel_launch(void* const* d_in, const int* in_sizes, int n_in,
                              void* d_out, int out_size, void* d_ws, size_t ws_size,
                              hipStream_t stream) {
    const float* s_prev = (const float*)d_in[0];
    const float* hidden = (const float*)d_in[1];
    const float* Ww     = (const float*)d_in[2];
    const float* Wb     = (const float*)d_in[3];
    const float* Uw     = (const float*)d_in[4];
    const float* Ub     = (const float*)d_in[5];
    const float* Vw     = (const float*)d_in[6];
    // d_in[7] = Vb: constant shift, cancels in softmax.

    float* out  = (float*)d_out;
    float* ctx  = out;                    // [32, 512]
    float* wout = out + BATCH * UNITS;    // [32, 4096, 1]

    float* wsf   = (float*)d_ws;
    float* ws_Ws = wsf;                                  // 16384 f32
    float* ws_lp = ws_Ws + BATCH * UNITS;                // 262144 f32
    float* ws_cp = ws_lp + (size_t)BATCH * SEQ * 2;      // 524288 f32
    __bf16* UwTt = (__bf16*)(ws_cp + (size_t)BATCH * 32 * UNITS);  // 512 KB bf16

    k_bprep<<<dim3(8, 2, 8), dim3(256), 0, stream>>>(Uw, UwTt);
    k_wsrow<<<dim3(32), dim3(256), 0, stream>>>(s_prev, Ww, Wb, Ub, ws_Ws);
    k_logits<<<dim3(1024), dim3(512), 0, stream>>>(hidden, UwTt, ws_Ws, Vw, ws_lp);
    k_softmax<<<dim3(32), dim3(256), 0, stream>>>(ws_lp, wout);
    k_ctxpart<<<dim3(32, 32), dim3(256), 0, stream>>>(hidden, wout, ws_cp);
    k_ctxreduce<<<dim3(32), dim3(512), 0, stream>>>(ws_cp, ctx);
}

// Round 8
// 238.903 us; speedup vs baseline: 1.0711x; 1.0711x over previous
//
#include <hip/hip_runtime.h>
#include <hip/hip_bf16.h>

#define UNITS 512
#define SEQ   4096
#define BATCH 32

typedef __attribute__((ext_vector_type(8))) __bf16 bf16x8;
typedef __attribute__((ext_vector_type(4))) float  f32x4;

// 128B-row LDS swizzle: swz128(r*128+x) = r*128 + (x ^ ((r&7)<<4)).
__device__ __forceinline__ int swz128(int l) { return l ^ (((l >> 7) & 7) << 4); }

#define MFMA(A, B, C) __builtin_amdgcn_mfma_f32_16x16x32_bf16(A, B, C, 0, 0, 0)
#define GLL(SRC, DST) __builtin_amdgcn_global_load_lds( \
    (const __attribute__((address_space(1))) void*)(SRC), \
    (__attribute__((address_space(3))) void*)(DST), 16, 0, 0)
#define PK8(X, Y) ({ bf16x8 _o; \
    _o[0]=(__bf16)(X).x; _o[1]=(__bf16)(X).y; _o[2]=(__bf16)(X).z; _o[3]=(__bf16)(X).w; \
    _o[4]=(__bf16)(Y).x; _o[5]=(__bf16)(Y).y; _o[6]=(__bf16)(Y).z; _o[7]=(__bf16)(Y).w; _o; })

// ---------------- K0: Uw [k][n] f32 -> UwTt: 16 tiles (ktile,gx) of 32KB --------
// Tile (t,gx): [n_local 256][k 64] bf16, 128B rows, stored PRE-SWIZZLED (swz128).
__global__ void k_bprep(const float* __restrict__ Uw, __bf16* __restrict__ UwTt) {
    const int c  = blockIdx.x;   // 16B chunk within 128B k-row (0..7)
    const int gx = blockIdx.y;   // n half
    const int t  = blockIdx.z;   // k-tile (0..7)
    const int nl = threadIdx.x;  // 0..255
    const int n  = gx * 256 + nl;
    const int k0 = t * 64 + c * 8;
    bf16x8 o;
#pragma unroll
    for (int j = 0; j < 8; j++)
        o[j] = (__bf16)Uw[(size_t)(k0 + j) * UNITS + n];
    char* dst = (char*)UwTt + (size_t)(t * 2 + gx) * 32768 + swz128(nl * 128 + c * 16);
    *(bf16x8*)dst = o;
}

// ---------------- KA: ws_Ws[b][v] = s_prev[b,:] @ Ww[:,v] + Wb[v] + Ub[v] --------
__global__ void k_wsrow(const float* __restrict__ s_prev, const float* __restrict__ Ww,
                        const float* __restrict__ Wb, const float* __restrict__ Ub,
                        float* __restrict__ ws_Ws) {
    __shared__ float sp[UNITS];
    int b = blockIdx.x, t = threadIdx.x;
    sp[t] = s_prev[b * UNITS + t];
    sp[t + 256] = s_prev[b * UNITS + t + 256];
    __syncthreads();
    float a0 = Wb[t] + Ub[t];
    float a1 = Wb[t + 256] + Ub[t + 256];
#pragma unroll 8
    for (int u = 0; u < UNITS; u++) {
        float s = sp[u];
        a0 += s * Ww[u * UNITS + t];
        a1 += s * Ww[u * UNITS + t + 256];
    }
    ws_Ws[b * UNITS + t] = a0;
    ws_Ws[b * UNITS + t + 256] = a1;
}

// ---------------- KB: fused  tanh(Ws + hidden@Uw) @ Vw  ->  logit partials -------
// 256x256 tile, 8 waves (2Mx4N, wave 128x64), BK=64, 8 K-tiles x 4 phases.
// Schedule fix vs r7: staging (cvt+ds_write, GLL, A-loads) strictly POST-MFMA;
// A regs loaded 2 tiles ahead (>=3 phases of HBM cover); counted vmcnt(8) at ph3
// (never drains the in-flight A-loads); lgkmcnt(0)+barrier only at tile boundary.
#define NT 8

__launch_bounds__(512)
__global__ void k_logits(const float* __restrict__ hidden, const __bf16* __restrict__ UwTt,
                         const float* __restrict__ wsu, const float* __restrict__ Vw,
                         float* __restrict__ lpart) {
    __shared__ __bf16 Ab[2][256 * 64];   // 32KB per buf, swz128
    __shared__ __bf16 Bb[2][256 * 64];   // 32KB per buf, pre-swizzled source
    __shared__ float  lred[256][4];      // 4KB -> 132KB total, 1 block/CU

    const int tid  = threadIdx.x;
    const int lane = tid & 63, wv = tid >> 6;
    const int wm = wv >> 2, wn = wv & 3;          // 2 x 4 -> wave tile 128x64
    const int l15 = lane & 15, l4 = lane >> 4;

    // block decode: both gx halves of a row-panel adjacent (L2 A dedup)
    const int id = blockIdx.x;                    // 0..1023
    const int gx = (id >> 3) & 1;
    const int y  = ((id >> 4) << 3) | (id & 7);   // 0..511
    const int m0 = y * 256;
    const int b  = m0 >> 12;

    const int xorv  = (l15 & 7) << 4;
    const int koff0 = (l4 * 16) ^ xorv;
    const int koff1 = (64 + l4 * 16) ^ xorv;
    const int aBase = wm * 16384 + l15 * 128;     // + fi*2048 + koff
    const int bBase = wn * 8192  + l15 * 128;     // + fj*2048 + koff

    // A staging: thread -> row sr (0..255), half sh; 32 f32 per tile
    const int sr = tid >> 1, sh = tid & 1;
    const float* aPtr = hidden + (size_t)(m0 + sr) * UNITS + sh * 32;
    const int wXor = (sr & 7) << 4;
    const int wo0 = sr * 128 + (((sh << 6) | 0 ) ^ wXor);
    const int wo1 = sr * 128 + (((sh << 6) | 16) ^ wXor);
    const int wo2 = sr * 128 + (((sh << 6) | 32) ^ wXor);
    const int wo3 = sr * 128 + (((sh << 6) | 48) ^ wXor);

    const char* bglBase = (const char*)UwTt + (size_t)gx * 32768 + wv * 4096 + lane * 16;

    f32x4 acc[8][4];
#pragma unroll
    for (int i = 0; i < 8; i++)
#pragma unroll
        for (int j = 0; j < 4; j++) acc[i][j] = (f32x4){0.f, 0.f, 0.f, 0.f};

    float4 la0, la1, la2, la3, la4, la5, la6, la7;   // loop-carried A stage regs

    // ---- prologue: stage tile 0; preload A regs for tile 1 ----
    {
        la0 = *(const float4*)(aPtr + 0);  la1 = *(const float4*)(aPtr + 4);
        la2 = *(const float4*)(aPtr + 8);  la3 = *(const float4*)(aPtr + 12);
        la4 = *(const float4*)(aPtr + 16); la5 = *(const float4*)(aPtr + 20);
        la6 = *(const float4*)(aPtr + 24); la7 = *(const float4*)(aPtr + 28);
        GLL(bglBase,        (char*)Bb[0] + wv * 4096);
        GLL(bglBase + 1024, (char*)Bb[0] + wv * 4096 + 1024);
        GLL(bglBase + 2048, (char*)Bb[0] + wv * 4096 + 2048);
        GLL(bglBase + 3072, (char*)Bb[0] + wv * 4096 + 3072);
        *(bf16x8*)((char*)Ab[0] + wo0) = PK8(la0, la1);   // auto vmcnt waits
        *(bf16x8*)((char*)Ab[0] + wo1) = PK8(la2, la3);
        *(bf16x8*)((char*)Ab[0] + wo2) = PK8(la4, la5);
        *(bf16x8*)((char*)Ab[0] + wo3) = PK8(la6, la7);
        la0 = *(const float4*)(aPtr + 64);  la1 = *(const float4*)(aPtr + 68);
        la2 = *(const float4*)(aPtr + 72);  la3 = *(const float4*)(aPtr + 76);
        la4 = *(const float4*)(aPtr + 80);  la5 = *(const float4*)(aPtr + 84);
        la6 = *(const float4*)(aPtr + 88);  la7 = *(const float4*)(aPtr + 92);
        asm volatile("s_waitcnt vmcnt(8) lgkmcnt(0)" ::: "memory");  // GLL-t0 done; 8 la in flight
        __builtin_amdgcn_s_barrier();
    }

#pragma unroll 2
    for (int kt = 0; kt < NT; ++kt) {
        char* Ac = (char*)Ab[kt & 1];
        char* Bc = (char*)Bb[kt & 1];
        char* An = (char*)Ab[(kt & 1) ^ 1];
        char* Bn = (char*)Bb[(kt & 1) ^ 1];
        const float* ap = aPtr + (kt + 2) * 64;              // A data for tile kt+2
        const char* bs  = bglBase + (size_t)(kt + 1) * 65536;

        bf16x8 bq[4][2];
        bf16x8 af0k0, af0k1, af1k0, af1k1;

        // ================= phase 0: fi 0,1 (+ B-held frags) =================
#pragma unroll
        for (int fj = 0; fj < 4; fj++) {
            bq[fj][0] = *(const bf16x8*)(Bc + bBase + fj * 2048 + koff0);
            bq[fj][1] = *(const bf16x8*)(Bc + bBase + fj * 2048 + koff1);
        }
        af0k0 = *(const bf16x8*)(Ac + aBase + 0 * 2048 + koff0);
        af0k1 = *(const bf16x8*)(Ac + aBase + 0 * 2048 + koff1);
        af1k0 = *(const bf16x8*)(Ac + aBase + 1 * 2048 + koff0);
        af1k1 = *(const bf16x8*)(Ac + aBase + 1 * 2048 + koff1);
        asm volatile("s_waitcnt lgkmcnt(0)" ::: "memory");
        __builtin_amdgcn_sched_barrier(0);
        __builtin_amdgcn_s_setprio(1);
#pragma unroll
        for (int fj = 0; fj < 4; fj++) {
            acc[0][fj] = MFMA(af0k0, bq[fj][0], acc[0][fj]);
            acc[0][fj] = MFMA(af0k1, bq[fj][1], acc[0][fj]);
            acc[1][fj] = MFMA(af1k0, bq[fj][0], acc[1][fj]);
            acc[1][fj] = MFMA(af1k1, bq[fj][1], acc[1][fj]);
        }
        __builtin_amdgcn_s_setprio(0);
        __builtin_amdgcn_sched_barrier(0);          // staging stays below MFMAs
        if (kt < NT - 1) {
            *(bf16x8*)(An + wo0) = PK8(la0, la1);   // A(kt+1) write, data loaded @ kt-1
            GLL(bs,        Bn + wv * 4096);
            GLL(bs + 1024, Bn + wv * 4096 + 1024);
            GLL(bs + 2048, Bn + wv * 4096 + 2048);
            GLL(bs + 3072, Bn + wv * 4096 + 3072);
        }
        __builtin_amdgcn_s_barrier();

        // ================= phase 1: fi 2,3 =================
        af0k0 = *(const bf16x8*)(Ac + aBase + 2 * 2048 + koff0);
        af0k1 = *(const bf16x8*)(Ac + aBase + 2 * 2048 + koff1);
        af1k0 = *(const bf16x8*)(Ac + aBase + 3 * 2048 + koff0);
        af1k1 = *(const bf16x8*)(Ac + aBase + 3 * 2048 + koff1);
        asm volatile("s_waitcnt lgkmcnt(0)" ::: "memory");
        __builtin_amdgcn_sched_barrier(0);
        __builtin_amdgcn_s_setprio(1);
#pragma unroll
        for (int fj = 0; fj < 4; fj++) {
            acc[2][fj] = MFMA(af0k0, bq[fj][0], acc[2][fj]);
            acc[2][fj] = MFMA(af0k1, bq[fj][1], acc[2][fj]);
            acc[3][fj] = MFMA(af1k0, bq[fj][0], acc[3][fj]);
            acc[3][fj] = MFMA(af1k1, bq[fj][1], acc[3][fj]);
        }
        __builtin_amdgcn_s_setprio(0);
        __builtin_amdgcn_sched_barrier(0);
        if (kt < NT - 1) *(bf16x8*)(An + wo1) = PK8(la2, la3);
        __builtin_amdgcn_s_barrier();

        // ================= phase 2: fi 4,5 (+ A-load for kt+2, first half) ======
        af0k0 = *(const bf16x8*)(Ac + aBase + 4 * 2048 + koff0);
        af0k1 = *(const bf16x8*)(Ac + aBase + 4 * 2048 + koff1);
        af1k0 = *(const bf16x8*)(Ac + aBase + 5 * 2048 + koff0);
        af1k1 = *(const bf16x8*)(Ac + aBase + 5 * 2048 + koff1);
        asm volatile("s_waitcnt lgkmcnt(0)" ::: "memory");
        __builtin_amdgcn_sched_barrier(0);
        __builtin_amdgcn_s_setprio(1);
#pragma unroll
        for (int fj = 0; fj < 4; fj++) {
            acc[4][fj] = MFMA(af0k0, bq[fj][0], acc[4][fj]);
            acc[4][fj] = MFMA(af0k1, bq[fj][1], acc[4][fj]);
            acc[5][fj] = MFMA(af1k0, bq[fj][0], acc[5][fj]);
            acc[5][fj] = MFMA(af1k1, bq[fj][1], acc[5][fj]);
        }
        __builtin_amdgcn_s_setprio(0);
        __builtin_amdgcn_sched_barrier(0);
        if (kt < NT - 1) *(bf16x8*)(An + wo2) = PK8(la4, la5);
        if (kt < NT - 2) {
            la0 = *(const float4*)(ap + 0);  la1 = *(const float4*)(ap + 4);
            la2 = *(const float4*)(ap + 8);  la3 = *(const float4*)(ap + 12);
        }
        __builtin_amdgcn_s_barrier();

        // ================= phase 3: fi 6,7 (+ A-load 2nd half, counted drain) ===
        af0k0 = *(const bf16x8*)(Ac + aBase + 6 * 2048 + koff0);
        af0k1 = *(const bf16x8*)(Ac + aBase + 6 * 2048 + koff1);
        af1k0 = *(const bf16x8*)(Ac + aBase + 7 * 2048 + koff0);
        af1k1 = *(const bf16x8*)(Ac + aBase + 7 * 2048 + koff1);
        asm volatile("s_waitcnt lgkmcnt(0)" ::: "memory");
        __builtin_amdgcn_sched_barrier(0);
        __builtin_amdgcn_s_setprio(1);
#pragma unroll
        for (int fj = 0; fj < 4; fj++) {
            acc[6][fj] = MFMA(af0k0, bq[fj][0], acc[6][fj]);
            acc[6][fj] = MFMA(af0k1, bq[fj][1], acc[6][fj]);
            acc[7][fj] = MFMA(af1k0, bq[fj][0], acc[7][fj]);
            acc[7][fj] = MFMA(af1k1, bq[fj][1], acc[7][fj]);
        }
        __builtin_amdgcn_s_setprio(0);
        __builtin_amdgcn_sched_barrier(0);
        if (kt < NT - 1) *(bf16x8*)(An + wo3) = PK8(la6, la7);
        if (kt < NT - 2) {
            la4 = *(const float4*)(ap + 16); la5 = *(const float4*)(ap + 20);
            la6 = *(const float4*)(ap + 24); la7 = *(const float4*)(ap + 28);
            asm volatile("s_waitcnt vmcnt(8) lgkmcnt(0)" ::: "memory"); // B(kt+1) landed; 8 la stay
        } else if (kt == NT - 2) {
            asm volatile("s_waitcnt vmcnt(0) lgkmcnt(0)" ::: "memory"); // last B drain
        }
        __builtin_amdgcn_s_barrier();
    }

    // epilogue: tanh(acc + Ws+Ub) * Vw, reduce over this block's 256 cols
    float wsub[4], vww[4];
#pragma unroll
    for (int fj = 0; fj < 4; fj++) {
        int n = gx * 256 + wn * 64 + fj * 16 + l15;
        wsub[fj] = wsu[b * UNITS + n];
        vww[fj]  = Vw[n];
    }
#pragma unroll
    for (int fi = 0; fi < 8; fi++) {
#pragma unroll
        for (int r = 0; r < 4; r++) {
            float p = 0.f;
#pragma unroll
            for (int fj = 0; fj < 4; fj++) {
                float x = acc[fi][fj][r] + wsub[fj];
                float e = __expf(2.f * x);
                p += vww[fj] * (1.f - 2.f / (e + 1.f));   // tanh(x)
            }
#pragma unroll
            for (int off = 1; off < 16; off <<= 1) p += __shfl_xor(p, off);
            if (l15 == 0) lred[wm * 128 + fi * 16 + l4 * 4 + r][wn] = p;
        }
    }
    __syncthreads();
    if (tid < 256) {
        float s = lred[tid][0] + lred[tid][1] + lred[tid][2] + lred[tid][3];
        lpart[(size_t)(m0 + tid) * 2 + gx] = s;
    }
}

// ---------------- KC: softmax over seq axis, write weights ----------------------
__global__ void k_softmax(const float* __restrict__ lpart, float* __restrict__ wout) {
    __shared__ float ebuf[SEQ];
    __shared__ float red[8];
    int b = blockIdx.x, t = threadIdx.x;
    int lane = t & 63, wv = t >> 6;
    float m = -1e30f;
#pragma unroll
    for (int i = 0; i < 16; i++) {
        int s = t + i * 256;
        size_t idx = ((size_t)b * SEQ + s) * 2;
        float l = lpart[idx] + lpart[idx + 1];
        ebuf[s] = l;
        m = fmaxf(m, l);
    }
#pragma unroll
    for (int off = 32; off >= 1; off >>= 1) m = fmaxf(m, __shfl_xor(m, off));
    if (lane == 0) red[wv] = m;
    __syncthreads();
    m = fmaxf(fmaxf(red[0], red[1]), fmaxf(red[2], red[3]));
    float zs = 0.f;
#pragma unroll
    for (int i = 0; i < 16; i++) {
        int s = t + i * 256;
        float e = __expf(ebuf[s] - m);
        ebuf[s] = e;
        zs += e;
    }
#pragma unroll
    for (int off = 32; off >= 1; off >>= 1) zs += __shfl_xor(zs, off);
    __syncthreads();
    if (lane == 0) red[wv] = zs;
    __syncthreads();
    float inv = 1.f / (red[0] + red[1] + red[2] + red[3]);
#pragma unroll
    for (int i = 0; i < 16; i++) {
        int s = t + i * 256;
        wout[(size_t)b * SEQ + s] = ebuf[s] * inv;
    }
}

// ---------------- KD: context partials over 128-seq chunks ----------------------
__global__ void k_ctxpart(const float* __restrict__ hidden, const float* __restrict__ wout,
                          float* __restrict__ part) {
    int b = blockIdx.y, c = blockIdx.x, t = threadIdx.x;
    const float* w = wout + (size_t)b * SEQ + c * 128;
    const float* h = hidden + ((size_t)b * SEQ + c * 128) * UNITS;
    float2 acc = make_float2(0.f, 0.f);
#pragma unroll 4
    for (int s = 0; s < 128; s++) {
        float ww = w[s];
        float2 v = ((const float2*)(h + (size_t)s * UNITS))[t];
        acc.x += ww * v.x;
        acc.y += ww * v.y;
    }
    ((float2*)(part + ((size_t)(b * 32 + c)) * UNITS))[t] = acc;
}

// ---------------- KE: reduce partials -> context --------------------------------
__global__ void k_ctxreduce(const float* __restrict__ part, float* __restrict__ ctx) {
    int b = blockIdx.x, t = threadIdx.x;
    float s = 0.f;
#pragma unroll
    for (int c = 0; c < 32; c++) s += part[((size_t)(b * 32 + c)) * UNITS + t];
    ctx[(size_t)b * UNITS + t] = s;
}

extern "C" void kernel_launch(void* const* d_in, const int* in_sizes, int n_in,
                              void* d_out, int out_size, void* d_ws, size_t ws_size,
                              hipStream_t stream) {
    const float* s_prev = (const float*)d_in[0];
    const float* hidden = (const float*)d_in[1];
    const float* Ww     = (const float*)d_in[2];
    const float* Wb     = (const float*)d_in[3];
    const float* Uw     = (const float*)d_in[4];
    const float* Ub     = (const float*)d_in[5];
    const float* Vw     = (const float*)d_in[6];
    // d_in[7] = Vb: constant shift, cancels in softmax.

    float* out  = (float*)d_out;
    float* ctx  = out;                    // [32, 512]
    float* wout = out + BATCH * UNITS;    // [32, 4096, 1]

    float* wsf   = (float*)d_ws;
    float* ws_Ws = wsf;                                  // 16384 f32
    float* ws_lp = ws_Ws + BATCH * UNITS;                // 262144 f32
    float* ws_cp = ws_lp + (size_t)BATCH * SEQ * 2;      // 524288 f32
    __bf16* UwTt = (__bf16*)(ws_cp + (size_t)BATCH * 32 * UNITS);  // 512 KB bf16

    k_bprep<<<dim3(8, 2, 8), dim3(256), 0, stream>>>(Uw, UwTt);
    k_wsrow<<<dim3(32), dim3(256), 0, stream>>>(s_prev, Ww, Wb, Ub, ws_Ws);
    k_logits<<<dim3(1024), dim3(512), 0, stream>>>(hidden, UwTt, ws_Ws, Vw, ws_lp);
    k_softmax<<<dim3(32), dim3(256), 0, stream>>>(ws_lp, wout);
    k_ctxpart<<<dim3(32, 32), dim3(256), 0, stream>>>(hidden, wout, ws_cp);
    k_ctxreduce<<<dim3(32), dim3(512), 0, stream>>>(ws_cp, ctx);
}

// Round 9
// 224.374 us; speedup vs baseline: 1.1404x; 1.0648x over previous
//
#include <hip/hip_runtime.h>
#include <hip/hip_bf16.h>

#define UNITS 512
#define SEQ   4096
#define BATCH 32

typedef __attribute__((ext_vector_type(8))) __bf16 bf16x8;
typedef __attribute__((ext_vector_type(4))) float  f32x4;

// LDS swizzle for 64B-stride rows: phys = l ^ (((l>>6)&7)<<4); bijective within
// each 128-row x 64B tile; same forward map on write and read.
__device__ __forceinline__ int swzB(int l) { return l ^ (((l >> 6) & 7) << 4); }

#define MFMA(A, B, C) __builtin_amdgcn_mfma_f32_16x16x32_bf16(A, B, C, 0, 0, 0)
#define GLL(SRC, DST) __builtin_amdgcn_global_load_lds( \
    (const __attribute__((address_space(1))) void*)(SRC), \
    (__attribute__((address_space(3))) void*)(DST), 16, 0, 0)

// ---------------- K0: Uw [k][n] f32 -> UwTt: 64 tiles (kstep 0..15, q 0..3) ------
// Tile (kstep,q) = [128 n][32 k] bf16 = 8KB, 64B rows, stored PRE-SWIZZLED (swzB)
// so k_logits stages with linear global_load_lds and reads with swzB.
__global__ void k_bprep(const float* __restrict__ Uw, __bf16* __restrict__ UwTt) {
    const int kstep = blockIdx.x;        // 0..15
    const int q     = blockIdx.y;        // 0..3
    const int t     = threadIdx.x;       // 0..255
    const int nl    = t & 127;
    const int h     = t >> 7;            // k-half (16 k each)
    const int n     = q * 128 + nl;
    const int k0    = kstep * 32 + h * 16;
    bf16x8 o0, o1;
#pragma unroll
    for (int j = 0; j < 8; j++) {
        o0[j] = (__bf16)Uw[(size_t)(k0 + j) * UNITS + n];
        o1[j] = (__bf16)Uw[(size_t)(k0 + 8 + j) * UNITS + n];
    }
    char* base = (char*)UwTt + (size_t)(kstep * 4 + q) * 8192;
    *(bf16x8*)(base + swzB(nl * 64 + h * 32))      = o0;
    *(bf16x8*)(base + swzB(nl * 64 + h * 32 + 16)) = o1;
}

// ---------------- KA: ws_Ws[b][v] = s_prev[b,:] @ Ww[:,v] + Wb[v] + Ub[v] --------
__global__ void k_wsrow(const float* __restrict__ s_prev, const float* __restrict__ Ww,
                        const float* __restrict__ Wb, const float* __restrict__ Ub,
                        float* __restrict__ ws_Ws) {
    __shared__ float sp[UNITS];
    int b = blockIdx.x, t = threadIdx.x;
    sp[t] = s_prev[b * UNITS + t];
    sp[t + 256] = s_prev[b * UNITS + t + 256];
    __syncthreads();
    float a0 = Wb[t] + Ub[t];
    float a1 = Wb[t + 256] + Ub[t + 256];
#pragma unroll 8
    for (int u = 0; u < UNITS; u++) {
        float s = sp[u];
        a0 += s * Ww[u * UNITS + t];
        a1 += s * Ww[u * UNITS + t + 256];
    }
    ws_Ws[b * UNITS + t] = a0;
    ws_Ws[b * UNITS + t + 256] = a1;
}

// ---------------- KB: fused  tanh(Ws + hidden@Uw) @ Vw  ->  logit partials -------
// m97-clone: 128x128 tile, BK=32, 256 thr (4 waves, 2x2, 64x64/wave), 34KB LDS,
// 4 blocks/CU, plain __syncthreads 2-barrier loop, compiler-scheduled waits.
// Block id encoding: id = (m&7) + 8*gx + 32*(m>>3) -> the 4 gx blocks of one
// A-panel share an XCD (id%8 == m%8) within a 32-id dispatch window (L2 dedup).
#define BM 128
#define BN 128
#define BK 32
#define NSTEP (UNITS / BK)

__launch_bounds__(256, 4)
__global__ void k_logits(const float* __restrict__ hidden, const __bf16* __restrict__ UwTt,
                         const float* __restrict__ wsu, const float* __restrict__ Vw,
                         float* __restrict__ lpart) {
    __shared__ __bf16 Ab[2][BM * BK];   // 8KB per buf, swzB
    __shared__ __bf16 Bb[2][BN * BK];   // 8KB per buf, pre-swizzled source
    __shared__ float  lred[BM][2];      // 1KB -> 34KB total

    const int t = threadIdx.x;
    const int lane = t & 63, wv = t >> 6;
    const int wm = wv >> 1, wn = wv & 1;          // 2 x 2 wave grid
    const int l15 = lane & 15, l4 = lane >> 4;

    const int id = blockIdx.x;                    // 0..4095
    const int gx = (id >> 3) & 3;
    const int mt = ((id >> 5) << 3) | (id & 7);   // 0..1023
    const int m0 = mt * BM;
    const int b  = m0 >> 12;

    f32x4 acc[4][4];
#pragma unroll
    for (int i = 0; i < 4; i++)
#pragma unroll
        for (int j = 0; j < 4; j++) acc[i][j] = (f32x4){0.f, 0.f, 0.f, 0.f};

    // ---- A staging: 256 thr x 16 f32 = 128 rows x 32 k per step ----
    const int sr = t >> 1;                   // row 0..127
    const int sh = t & 1;                    // k-half (16 f32)
    const float* aRow = hidden + (size_t)(m0 + sr) * UNITS + sh * 16;
    const int aw0 = swzB(sr * 64 + sh * 32);
    const int aw1 = swzB(sr * 64 + sh * 32 + 16);

    int aoffR[4], boffR[4];
#pragma unroll
    for (int f = 0; f < 4; f++) {
        aoffR[f] = swzB((wm * 64 + f * 16 + l15) * 64 + l4 * 16);
        boffR[f] = swzB((wn * 64 + f * 16 + l15) * 64 + l4 * 16);
    }

    const char* bglBase = (const char*)UwTt + (size_t)gx * 8192 + wv * 2048 + lane * 16;

    // prologue: stage step 0 into buf 0
    {
        float4 v0 = *(const float4*)(aRow);
        float4 v1 = *(const float4*)(aRow + 4);
        float4 v2 = *(const float4*)(aRow + 8);
        float4 v3 = *(const float4*)(aRow + 12);
        GLL(bglBase,        (char*)Bb[0] + wv * 2048);
        GLL(bglBase + 1024, (char*)Bb[0] + wv * 2048 + 1024);
        bf16x8 o0, o1;
        o0[0]=(__bf16)v0.x; o0[1]=(__bf16)v0.y; o0[2]=(__bf16)v0.z; o0[3]=(__bf16)v0.w;
        o0[4]=(__bf16)v1.x; o0[5]=(__bf16)v1.y; o0[6]=(__bf16)v1.z; o0[7]=(__bf16)v1.w;
        o1[0]=(__bf16)v2.x; o1[1]=(__bf16)v2.y; o1[2]=(__bf16)v2.z; o1[3]=(__bf16)v2.w;
        o1[4]=(__bf16)v3.x; o1[5]=(__bf16)v3.y; o1[6]=(__bf16)v3.z; o1[7]=(__bf16)v3.w;
        *(bf16x8*)((char*)Ab[0] + aw0) = o0;
        *(bf16x8*)((char*)Ab[0] + aw1) = o1;
    }

#pragma unroll 2
    for (int s = 0; s < NSTEP; ++s) {
        const int cur = s & 1;
        __syncthreads();   // compiler emits vmcnt(0) lgkmcnt(0) drain + barrier

        // issue next step's loads early (fresh locals each iteration: no carry)
        float4 v0, v1, v2, v3;
        if (s + 1 < NSTEP) {
            v0 = *(const float4*)(aRow + (s + 1) * BK);
            v1 = *(const float4*)(aRow + (s + 1) * BK + 4);
            v2 = *(const float4*)(aRow + (s + 1) * BK + 8);
            v3 = *(const float4*)(aRow + (s + 1) * BK + 12);
            GLL(bglBase + (size_t)((s + 1) * 4) * 8192,
                (char*)Bb[cur ^ 1] + wv * 2048);
            GLL(bglBase + (size_t)((s + 1) * 4) * 8192 + 1024,
                (char*)Bb[cur ^ 1] + wv * 2048 + 1024);
        }

        bf16x8 a[4], bq[4];
#pragma unroll
        for (int fi = 0; fi < 4; fi++)
            a[fi] = *(const bf16x8*)((const char*)Ab[cur] + aoffR[fi]);
#pragma unroll
        for (int fj = 0; fj < 4; fj++)
            bq[fj] = *(const bf16x8*)((const char*)Bb[cur] + boffR[fj]);
#pragma unroll
        for (int fi = 0; fi < 4; fi++)
#pragma unroll
            for (int fj = 0; fj < 4; fj++)
                acc[fi][fj] = MFMA(a[fi], bq[fj], acc[fi][fj]);

        if (s + 1 < NSTEP) {
            bf16x8 o0, o1;
            o0[0]=(__bf16)v0.x; o0[1]=(__bf16)v0.y; o0[2]=(__bf16)v0.z; o0[3]=(__bf16)v0.w;
            o0[4]=(__bf16)v1.x; o0[5]=(__bf16)v1.y; o0[6]=(__bf16)v1.z; o0[7]=(__bf16)v1.w;
            o1[0]=(__bf16)v2.x; o1[1]=(__bf16)v2.y; o1[2]=(__bf16)v2.z; o1[3]=(__bf16)v2.w;
            o1[4]=(__bf16)v3.x; o1[5]=(__bf16)v3.y; o1[6]=(__bf16)v3.z; o1[7]=(__bf16)v3.w;
            *(bf16x8*)((char*)Ab[cur ^ 1] + aw0) = o0;
            *(bf16x8*)((char*)Ab[cur ^ 1] + aw1) = o1;
        }
    }

    // epilogue: tanh(acc + Ws+Ub) * Vw, reduce over this block's 128 cols
    float wsub[4], vww[4];
#pragma unroll
    for (int fj = 0; fj < 4; fj++) {
        int n = gx * BN + wn * 64 + fj * 16 + l15;
        wsub[fj] = wsu[b * UNITS + n];
        vww[fj]  = Vw[n];
    }
#pragma unroll
    for (int fi = 0; fi < 4; fi++) {
#pragma unroll
        for (int r = 0; r < 4; r++) {
            float p = 0.f;
#pragma unroll
            for (int fj = 0; fj < 4; fj++) {
                float x = acc[fi][fj][r] + wsub[fj];
                float e = __expf(2.f * x);
                p += vww[fj] * (1.f - 2.f / (e + 1.f));   // tanh(x)
            }
#pragma unroll
            for (int off = 1; off < 16; off <<= 1) p += __shfl_xor(p, off);
            if (l15 == 0) lred[wm * 64 + fi * 16 + l4 * 4 + r][wn] = p;
        }
    }
    __syncthreads();
    if (t < BM) {
        lpart[(size_t)(m0 + t) * 4 + gx] = lred[t][0] + lred[t][1];
    }
}

// ---------------- KC: softmax over seq axis, write weights ----------------------
__global__ void k_softmax(const float* __restrict__ lpart, float* __restrict__ wout) {
    __shared__ float ebuf[SEQ];
    __shared__ float red[8];
    int b = blockIdx.x, t = threadIdx.x;
    int lane = t & 63, wv = t >> 6;
    float m = -1e30f;
#pragma unroll
    for (int i = 0; i < 16; i++) {
        int s = t + i * 256;
        size_t idx = ((size_t)b * SEQ + s) * 4;
        float l = (lpart[idx] + lpart[idx + 1]) + (lpart[idx + 2] + lpart[idx + 3]);
        ebuf[s] = l;
        m = fmaxf(m, l);
    }
#pragma unroll
    for (int off = 32; off >= 1; off >>= 1) m = fmaxf(m, __shfl_xor(m, off));
    if (lane == 0) red[wv] = m;
    __syncthreads();
    m = fmaxf(fmaxf(red[0], red[1]), fmaxf(red[2], red[3]));
    float zs = 0.f;
#pragma unroll
    for (int i = 0; i < 16; i++) {
        int s = t + i * 256;
        float e = __expf(ebuf[s] - m);
        ebuf[s] = e;
        zs += e;
    }
#pragma unroll
    for (int off = 32; off >= 1; off >>= 1) zs += __shfl_xor(zs, off);
    __syncthreads();
    if (lane == 0) red[wv] = zs;
    __syncthreads();
    float inv = 1.f / (red[0] + red[1] + red[2] + red[3]);
#pragma unroll
    for (int i = 0; i < 16; i++) {
        int s = t + i * 256;
        wout[(size_t)b * SEQ + s] = ebuf[s] * inv;
    }
}

// ---------------- KD: context partials over 128-seq chunks ----------------------
__global__ void k_ctxpart(const float* __restrict__ hidden, const float* __restrict__ wout,
                          float* __restrict__ part) {
    int b = blockIdx.y, c = blockIdx.x, t = threadIdx.x;
    const float* w = wout + (size_t)b * SEQ + c * 128;
    const float* h = hidden + ((size_t)b * SEQ + c * 128) * UNITS;
    float2 acc = make_float2(0.f, 0.f);
#pragma unroll 4
    for (int s = 0; s < 128; s++) {
        float ww = w[s];
        float2 v = ((const float2*)(h + (size_t)s * UNITS))[t];
        acc.x += ww * v.x;
        acc.y += ww * v.y;
    }
    ((float2*)(part + ((size_t)(b * 32 + c)) * UNITS))[t] = acc;
}

// ---------------- KE: reduce partials -> context --------------------------------
__global__ void k_ctxreduce(const float* __restrict__ part, float* __restrict__ ctx) {
    int b = blockIdx.x, t = threadIdx.x;
    float s = 0.f;
#pragma unroll
    for (int c = 0; c < 32; c++) s += part[((size_t)(b * 32 + c)) * UNITS + t];
    ctx[(size_t)b * UNITS + t] = s;
}

extern "C" void kernel_launch(void* const* d_in, const int* in_sizes, int n_in,
                              void* d_out, int out_size, void* d_ws, size_t ws_size,
                              hipStream_t stream) {
    const float* s_prev = (const float*)d_in[0];
    const float* hidden = (const float*)d_in[1];
    const float* Ww     = (const float*)d_in[2];
    const float* Wb     = (const float*)d_in[3];
    const float* Uw     = (const float*)d_in[4];
    const float* Ub     = (const float*)d_in[5];
    const float* Vw     = (const float*)d_in[6];
    // d_in[7] = Vb: constant shift, cancels in softmax.

    float* out  = (float*)d_out;
    float* ctx  = out;                    // [32, 512]
    float* wout = out + BATCH * UNITS;    // [32, 4096, 1]

    float* wsf   = (float*)d_ws;
    float* ws_Ws = wsf;                                  // 16384 f32
    float* ws_lp = ws_Ws + BATCH * UNITS;                // 524288 f32 (4 quarters)
    float* ws_cp = ws_lp + (size_t)BATCH * SEQ * 4;      // 524288 f32
    __bf16* UwTt = (__bf16*)(ws_cp + (size_t)BATCH * 32 * UNITS);  // 512 KB bf16

    k_bprep<<<dim3(16, 4), dim3(256), 0, stream>>>(Uw, UwTt);
    k_wsrow<<<dim3(32), dim3(256), 0, stream>>>(s_prev, Ww, Wb, Ub, ws_Ws);
    k_logits<<<dim3(4096), dim3(256), 0, stream>>>(hidden, UwTt, ws_Ws, Vw, ws_lp);
    k_softmax<<<dim3(32), dim3(256), 0, stream>>>(ws_lp, wout);
    k_ctxpart<<<dim3(32, 32), dim3(256), 0, stream>>>(hidden, wout, ws_cp);
    k_ctxreduce<<<dim3(32), dim3(512), 0, stream>>>(ws_cp, ctx);
}